// Round 11
// baseline (497.058 us; speedup 1.0000x reference)
//
#include <hip/hip_runtime.h>
#include <hip/hip_bf16.h>

#define D 128
#define NP 8           // src-range sub-buckets per dst (csr slice order)
#define DPB 64         // dst per coarse bucket (b = d>>6)
#define KPB (DPB * NP) // fine keys per bucket = 512
#define SUB 64         // sub-cursors per bucket
#define CAP_SUB 64     // staging capacity per (sub, bucket); mean 16

typedef __attribute__((ext_vector_type(8))) __bf16 bf16x8;
typedef __attribute__((ext_vector_type(4))) float f32x4;
typedef __attribute__((ext_vector_type(4))) short s16x4;
typedef __attribute__((ext_vector_type(8))) short s16x8;

static __device__ __forceinline__ short f2bf(float f) {
    union { float f; unsigned u; } in; in.f = f;
    unsigned u = in.u;
    u += 0x7fffu + ((u >> 16) & 1u);   // round-to-nearest-even
    return (short)(u >> 16);
}

// ---- phase 1: coarse-bucket edges; 100K sub-cursors kill contention ----
// pack: fineKey(9b: (d&63)*8 + (src>>14)) << 17 | src(17b)   [N < 2^17]
__global__ void k_bucket(const int* __restrict__ src, const int* __restrict__ dst,
                         int* __restrict__ bcnt, int* __restrict__ staging,
                         int E, int KBE) {
    int i = blockIdx.x * 256 + threadIdx.x;
    if (i >= E) return;
    int d = dst[i], s = src[i];
    int b = d >> 6;
    int key = ((d & 63) << 3) | (s >> 14);
    int j = blockIdx.x & (SUB - 1);      // j%8 == heuristic XCD
    int slot = atomicAdd(&bcnt[j * KBE + b], 1);
    if (slot < CAP_SUB) staging[((size_t)j * KBE + b) * CAP_SUB + slot] = (key << 17) | s;
}

// ---- per-bucket totals (parallel, coalesced per-j stripes) ----
__global__ void k_btot(const int* __restrict__ bcnt, int* __restrict__ btot, int KBE) {
    int b = blockIdx.x * 256 + threadIdx.x;
    if (b >= KBE) return;
    int v = 0;
    #pragma unroll
    for (int j = 0; j < SUB; j++) {
        int c = bcnt[j * KBE + b];
        v += (c > CAP_SUB) ? CAP_SUB : c;
    }
    btot[b] = v;
}

// ---- exclusive scan of bucket totals (single block, chunked) ----
__global__ void k_bscan(const int* __restrict__ btot, int* __restrict__ bbase,
                        int* __restrict__ row_ptr, int nkeys, int KBE) {
    __shared__ int sm[512];
    __shared__ int carry;
    int t = threadIdx.x;
    if (t == 0) carry = 0;
    __syncthreads();
    for (int c0 = 0; c0 < KBE; c0 += 512) {
        int b = c0 + t;
        int v = (b < KBE) ? btot[b] : 0;
        sm[t] = v;
        __syncthreads();
        for (int off = 1; off < 512; off <<= 1) {
            int x = (t >= off) ? sm[t - off] : 0;
            __syncthreads();
            sm[t] += x;
            __syncthreads();
        }
        if (b < KBE) bbase[b] = sm[t] - v + carry;
        __syncthreads();
        if (t == 0) carry += sm[511];
        __syncthreads();
    }
    if (t == 0) { bbase[KBE] = carry; row_ptr[nkeys] = carry; }
}

// ---- phase 2: per-bucket fine CSR build in LDS + degree-balanced perm ----
// thread t owns lane (t&3) of sub-region j = t>>2  (4 threads per sub)
__global__ __launch_bounds__(256) void k_build(
    const int* __restrict__ staging, const int* __restrict__ bcnt,
    const int* __restrict__ bbase, int* __restrict__ row_ptr,
    int* __restrict__ csr_src, float* __restrict__ dinv,
    int* __restrict__ perm, int N, int KBE)
{
    const int b = blockIdx.x;
    const int tid = threadIdx.x;
    __shared__ int cnt[KPB];
    __shared__ int subn[SUB];
    __shared__ int sdeg[DPB];
    __shared__ int chunkbuf[256];
    __shared__ int carry;

    if (tid < SUB) {
        int c = bcnt[tid * KBE + b];
        subn[tid] = (c > CAP_SUB) ? CAP_SUB : c;
    }
    for (int k = tid; k < KPB; k += 256) cnt[k] = 0;
    if (tid == 0) carry = 0;
    __syncthreads();

    const int base = bbase[b];
    const int nb = bbase[b + 1] - base;          // bucket total (from scan)
    const int j = tid >> 2, l4 = tid & 3;
    const int* __restrict__ sreg = staging + ((size_t)j * KBE + b) * CAP_SUB;
    const int sn = subn[j];

    // histogram over fine keys
    for (int e = l4; e < sn; e += 4)
        atomicAdd(&cnt[sreg[e] >> 17], 1);
    __syncthreads();

    // in-place exclusive scan of cnt[0..KPB)  (2 chunks of 256)
    #pragma unroll 1
    for (int c = 0; c < KPB / 256; c++) {
        int idx = c * 256 + tid;
        int v = cnt[idx];
        chunkbuf[tid] = v;
        __syncthreads();
        for (int off = 1; off < 256; off <<= 1) {
            int x = (tid >= off) ? chunkbuf[tid - off] : 0;
            __syncthreads();
            chunkbuf[tid] += x;
            __syncthreads();
        }
        cnt[idx] = chunkbuf[tid] - v + carry;
        __syncthreads();
        if (tid == 255) carry += chunkbuf[255];
        __syncthreads();
    }

    for (int k = tid; k < KPB; k += 256)
        row_ptr[(size_t)b * KPB + k] = base + cnt[k];
    if (tid < DPB) {
        int dl = tid;
        int d = b * DPB + dl;
        int hi2 = (dl == DPB - 1) ? nb : cnt[(dl + 1) * NP];
        int deg = hi2 - cnt[dl * NP];
        if (d < N) {
            dinv[d] = rsqrtf((float)deg + 1.0f);
            sdeg[dl] = deg;
        } else {
            sdeg[dl] = 0x7FFFFFFF;    // invalid nodes sort last
        }
    }
    __syncthreads();

    // scatter into this bucket's contiguous csr region (LDS cursors)
    for (int e = l4; e < sn; e += 4) {
        int w = sreg[e];
        int slot = base + atomicAdd(&cnt[w >> 17], 1);
        csr_src[slot] = w & 0x1FFFF;
    }

    // degree rank-sort of the bucket's 64 nodes -> perm (balanced k_layer blocks)
    if (tid < DPB) {
        int mydeg = sdeg[tid];
        int rank = 0;
        #pragma unroll
        for (int q = 0; q < DPB; q++) {
            int dq = sdeg[q];
            rank += (dq < mydeg) || (dq == mydeg && q < tid);
        }
        perm[b * DPB + rank] = b * DPB + tid;
    }
}

// ---- batch is SORTED: segment starts AND counts via binary search ----
__global__ void k_gseg(const int* __restrict__ batch, int* __restrict__ gstart,
                       int* __restrict__ gcnt, int N, int B) {
    int g = blockIdx.x * blockDim.x + threadIdx.x;
    if (g > B) return;
    int lo = 0, hi = N;
    while (lo < hi) {
        int mid = (lo + hi) >> 1;
        if (batch[mid] < g) lo = mid + 1; else hi = mid;
    }
    gstart[g] = lo;
    if (g < B) {
        int lo2 = lo, hi2 = N;
        while (lo2 < hi2) {
            int mid = (lo2 + hi2) >> 1;
            if (batch[mid] < g + 1) lo2 = mid + 1; else hi2 = mid;
        }
        gcnt[g] = lo2 - lo;
    }
}

// ---- x' = dinv[i] * x  -> bf16 (pre-scaled feature rows) ----
__global__ void k_cvt_x(const float* __restrict__ x, const float* __restrict__ dinv,
                        short* __restrict__ xb, int total4) {
    int i = blockIdx.x * blockDim.x + threadIdx.x;
    if (i < total4) {
        float d = dinv[i >> 5];
        float4 v = ((const float4*)x)[i];
        s16x4 o;
        o.x = f2bf(v.x * d); o.y = f2bf(v.y * d);
        o.z = f2bf(v.z * d); o.w = f2bf(v.w * d);
        ((s16x4*)xb)[i] = o;
    }
}

// ---- conv_w: fp32 [L][k][n] -> bf16 transposed [L][n][k] ----
__global__ void k_cvt_w(const float* __restrict__ W, short* __restrict__ Wt, int total) {
    int i = blockIdx.x * blockDim.x + threadIdx.x;
    if (i < total) {
        int l = i >> 14;
        int rem = i & 16383;
        int n = rem >> 7;
        int k = rem & 127;
        Wt[i] = f2bf(W[(l << 14) + (k << 7) + n]);
    }
}

// ---- FUSED layer v3: degree-balanced nodes, flat 8-deep gather chains ----
// 16 concurrent nodes/block (1 per 16-lane group) -> 4KB LDS tile -> 1 barrier
// -> cooperative 16x128 MFMA GEMM (wave w = 32 cols).
// mode 0: hout[r] = bf16( relu(C + b) * dinv[r] );  mode 1: hrelu[r] = fp32 relu(C+b)
__global__ __launch_bounds__(256) void k_layer(
    const short* __restrict__ hin, const int* __restrict__ row_ptr,
    const int* __restrict__ csr_src, const float* __restrict__ dinv,
    const int* __restrict__ perm, const short* __restrict__ Wt,
    const float* __restrict__ bias, short* __restrict__ hout,
    float* __restrict__ hrelu, int N, int mode)
{
    __shared__ __align__(16) short tile[16 * 128];   // 4 KB, swizzled 16B chunks
    __shared__ int snode[16];
    const int tid = threadIdx.x;
    const int wave = tid >> 6;
    const int lane = tid & 63;
    const int group = lane >> 4;
    const int lg = lane & 15;
    const int off = lg * 8;
    const int node_base = blockIdx.x * 16;
    const int r = wave * 4 + group;          // tile row this group owns (0..15)
    const int i = perm[node_base + r];       // degree-balanced node id
    if (lg == 0) snode[r] = i;

    // ---- phase 1: aggregate one node per group, flat 8-deep chains ----
    short* dstp = &tile[r * 128 + ((lg ^ (r & 7)) << 3)];
    if (i < N) {
        float acc[8];
        bf16x8 v = *(const bf16x8*)(hin + (size_t)i * D + off);
        #pragma unroll
        for (int k = 0; k < 8; k++) acc[k] = (float)v[k];
        int t = row_ptr[i * NP];
        const int end = row_ptr[i * NP + NP];

        for (; t + 8 <= end; t += 8) {       // 8 outstanding row loads
            int i0 = csr_src[t + 0], i1 = csr_src[t + 1];
            int i2 = csr_src[t + 2], i3 = csr_src[t + 3];
            int i4 = csr_src[t + 4], i5 = csr_src[t + 5];
            int i6 = csr_src[t + 6], i7 = csr_src[t + 7];
            bf16x8 v0 = *(const bf16x8*)(hin + (size_t)i0 * D + off);
            bf16x8 v1 = *(const bf16x8*)(hin + (size_t)i1 * D + off);
            bf16x8 v2 = *(const bf16x8*)(hin + (size_t)i2 * D + off);
            bf16x8 v3 = *(const bf16x8*)(hin + (size_t)i3 * D + off);
            bf16x8 v4 = *(const bf16x8*)(hin + (size_t)i4 * D + off);
            bf16x8 v5 = *(const bf16x8*)(hin + (size_t)i5 * D + off);
            bf16x8 v6 = *(const bf16x8*)(hin + (size_t)i6 * D + off);
            bf16x8 v7 = *(const bf16x8*)(hin + (size_t)i7 * D + off);
            #pragma unroll
            for (int k = 0; k < 8; k++)
                acc[k] += (((float)v0[k] + (float)v1[k]) + ((float)v2[k] + (float)v3[k]))
                        + (((float)v4[k] + (float)v5[k]) + ((float)v6[k] + (float)v7[k]));
        }
        if (t + 4 <= end) {                  // 4-deep tail
            int i0 = csr_src[t + 0], i1 = csr_src[t + 1];
            int i2 = csr_src[t + 2], i3 = csr_src[t + 3];
            bf16x8 v0 = *(const bf16x8*)(hin + (size_t)i0 * D + off);
            bf16x8 v1 = *(const bf16x8*)(hin + (size_t)i1 * D + off);
            bf16x8 v2 = *(const bf16x8*)(hin + (size_t)i2 * D + off);
            bf16x8 v3 = *(const bf16x8*)(hin + (size_t)i3 * D + off);
            #pragma unroll
            for (int k = 0; k < 8; k++)
                acc[k] += (((float)v0[k] + (float)v1[k]) + ((float)v2[k] + (float)v3[k]));
            t += 4;
        }
        for (; t < end; t++) {               // scalar tail
            int i0 = csr_src[t];
            bf16x8 v0 = *(const bf16x8*)(hin + (size_t)i0 * D + off);
            #pragma unroll
            for (int k = 0; k < 8; k++) acc[k] += (float)v0[k];
        }

        const float di = dinv[i];
        s16x8 o;
        #pragma unroll
        for (int k = 0; k < 8; k++) o[k] = f2bf(acc[k] * di);
        *(s16x8*)dstp = o;
    } else {
        s16x8 z = {0, 0, 0, 0, 0, 0, 0, 0};
        *(s16x8*)dstp = z;
    }
    __syncthreads();

    // ---- phase 2: cooperative GEMM; wave w computes cols [w*32, w*32+32) ----
    bf16x8 afrag[4];
    #pragma unroll
    for (int kt = 0; kt < 4; kt++)
        afrag[kt] = *(const bf16x8*)(&tile[lg * 128 + (((group + 4 * kt) ^ (lg & 7)) << 3)]);

    f32x4 acc2[2];
    #pragma unroll
    for (int nt = 0; nt < 2; nt++) { f32x4 z = {0.f, 0.f, 0.f, 0.f}; acc2[nt] = z; }
    #pragma unroll
    for (int nt = 0; nt < 2; nt++) {
        const short* bp = Wt + (size_t)(wave * 32 + nt * 16 + lg) * D + group * 8;
        #pragma unroll
        for (int kt = 0; kt < 4; kt++) {
            bf16x8 b = *(const bf16x8*)(bp + kt * 32);
            acc2[nt] = __builtin_amdgcn_mfma_f32_16x16x32_bf16(afrag[kt], b, acc2[nt], 0, 0, 0);
        }
    }

    // C/D layout: col = lane&15, row = (lane>>4)*4 + reg  (tile row -> snode)
    float bcol[2];
    #pragma unroll
    for (int nt = 0; nt < 2; nt++) bcol[nt] = bias[wave * 32 + nt * 16 + lg];
    #pragma unroll
    for (int i2 = 0; i2 < 4; i2++) {
        int r2 = snode[group * 4 + i2];
        if (r2 < N) {
            if (mode == 0) {
                float dr = dinv[r2];
                #pragma unroll
                for (int nt = 0; nt < 2; nt++) {
                    int col = wave * 32 + nt * 16 + lg;
                    float val = fmaxf(acc2[nt][i2] + bcol[nt], 0.0f);
                    hout[(size_t)r2 * D + col] = f2bf(val * dr);
                }
            } else {
                #pragma unroll
                for (int nt = 0; nt < 2; nt++) {
                    int col = wave * 32 + nt * 16 + lg;
                    hrelu[(size_t)r2 * D + col] = fmaxf(acc2[nt][i2] + bcol[nt], 0.0f);
                }
            }
        }
    }
}

// ---- segmented pooling, 4-way row-split per graph for latency hiding ----
__global__ __launch_bounds__(256) void k_pool(const float* __restrict__ hrelu,
                                              const int* __restrict__ gstart,
                                              const int* __restrict__ gcnt,
                                              float* __restrict__ pmax,
                                              float* __restrict__ psum, int B) {
    int g = blockIdx.x >> 2;
    int q = blockIdx.x & 3;
    int c = threadIdx.x & 127;
    int p = threadIdx.x >> 7;
    int start = gstart[g];
    int endr = start + gcnt[g];

    float mx0 = 0.f, mx1 = 0.f, sm0 = 0.f, sm1 = 0.f;
    int r = start + q * 2 + p;
    for (; r + 8 < endr; r += 16) {
        float v0 = hrelu[(size_t)r * D + c];
        float v1 = hrelu[(size_t)(r + 8) * D + c];
        mx0 = fmaxf(mx0, v0); sm0 += v0;
        mx1 = fmaxf(mx1, v1); sm1 += v1;
    }
    if (r < endr) {
        float v0 = hrelu[(size_t)r * D + c];
        mx0 = fmaxf(mx0, v0); sm0 += v0;
    }
    float mx = fmaxf(mx0, mx1), sm = sm0 + sm1;

    __shared__ float smx[128], ssm[128];
    if (p == 1) { smx[c] = mx; ssm[c] = sm; }
    __syncthreads();
    if (p == 0) {
        pmax[((size_t)q * B + g) * D + c] = fmaxf(mx, smx[c]);
        psum[((size_t)q * B + g) * D + c] = sm + ssm[c];
    }
}

// ---- final: combine 4 partials; out[g] = [gmax, gsum/cnt, gsum] @ out_w + out_b ----
__global__ void k_final(const float* __restrict__ pmax, const float* __restrict__ psum,
                        const int* __restrict__ gcnt, const float* __restrict__ ow,
                        const float* __restrict__ ob, float* __restrict__ out, int B) {
    int g = blockIdx.x;
    int t = threadIdx.x;  // 64
    float part[10];
    #pragma unroll
    for (int o = 0; o < 10; o++) part[o] = 0.f;
    float invc = 1.0f / fmaxf((float)gcnt[g], 1.0f);
    for (int k = t; k < 3 * D; k += 64) {
        int c = (k < D) ? k : ((k < 2 * D) ? k - D : k - 2 * D);
        float pk;
        if (k < D) {
            float m = pmax[(size_t)g * D + c];
            #pragma unroll
            for (int q = 1; q < 4; q++) m = fmaxf(m, pmax[((size_t)q * B + g) * D + c]);
            pk = m;
        } else {
            float s = psum[(size_t)g * D + c];
            #pragma unroll
            for (int q = 1; q < 4; q++) s += psum[((size_t)q * B + g) * D + c];
            pk = (k < 2 * D) ? s * invc : s;
        }
        const float* w = ow + k * 10;
        #pragma unroll
        for (int o = 0; o < 10; o++) part[o] += pk * w[o];
    }
    #pragma unroll
    for (int off = 32; off > 0; off >>= 1)
        #pragma unroll
        for (int o = 0; o < 10; o++) part[o] += __shfl_down(part[o], off, 64);
    if (t == 0)
        #pragma unroll
        for (int o = 0; o < 10; o++) out[g * 10 + o] = part[o] + ob[o];
}

extern "C" void kernel_launch(void* const* d_in, const int* in_sizes, int n_in,
                              void* d_out, int out_size, void* d_ws, size_t ws_size,
                              hipStream_t stream) {
    const float* x     = (const float*)d_in[0];
    const int*   ei    = (const int*)d_in[1];
    const int*   batch = (const int*)d_in[2];
    const float* convw = (const float*)d_in[3];
    const float* convb = (const float*)d_in[4];
    const float* outw  = (const float*)d_in[5];
    const float* outb  = (const float*)d_in[6];
    float* out = (float*)d_out;

    const int N = in_sizes[0] / D;        // 100000
    const int E = in_sizes[1] / 2;        // 1600000
    const int L = in_sizes[3] / (D * D);  // 3
    const int B = out_size / 10;          // 256

    const int* src = ei;
    const int* dst = ei + E;

    const int KBE   = (N + DPB - 1) / DPB;     // coarse buckets (1563)
    const int nkeys = KBE * KPB;               // global fine-key space

    char* p = (char*)d_ws;
    auto alloc = [&](size_t bytes) { char* r = p; p += (bytes + 255) & ~255ull; return r; };
    short* hb0     = (short*)alloc((size_t)N * D * 2);      // ping-pong bf16 rows
    short* hb1     = (short*)alloc((size_t)N * D * 2);
    float* hrelu   = (float*)alloc((size_t)N * D * 4);      // fp32 last-layer relu; ALIASED as staging
    short* Wt      = (short*)alloc((size_t)L * D * D * 2);  // bf16 W^T
    int*   row_ptr = (int*)alloc(((size_t)nkeys + 1) * 4);
    int*   csr_src = (int*)alloc((size_t)E * 4);
    int*   bcnt    = (int*)alloc((size_t)SUB * KBE * 4);
    int*   btot    = (int*)alloc((size_t)KBE * 4);
    int*   bbase   = (int*)alloc(((size_t)KBE + 1) * 4);
    int*   perm    = (int*)alloc((size_t)KBE * DPB * 4);
    float* dinv    = (float*)alloc((size_t)N * 4);
    float* pmax    = (float*)alloc((size_t)4 * B * D * 4);
    float* psum    = (float*)alloc((size_t)4 * B * D * 4);
    int*   gcnt    = (int*)alloc((size_t)B * 4);
    int*   gstart  = (int*)alloc(((size_t)B + 1) * 4);

    // staging: SUB*KBE*CAP_SUB*4 = 64*1563*64*4 = 25.6 MB <= hrelu's 51.2 MB
    int* staging = (int*)hrelu;   // hrelu written only after k_build completes

    hipMemsetAsync(bcnt, 0, (size_t)SUB * KBE * 4, stream);

    k_bucket<<<(E + 255) / 256, 256, 0, stream>>>(src, dst, bcnt, staging, E, KBE);
    k_gseg<<<1, 512, 0, stream>>>(batch, gstart, gcnt, N, B);
    k_btot<<<(KBE + 255) / 256, 256, 0, stream>>>(bcnt, btot, KBE);
    k_bscan<<<1, 512, 0, stream>>>(btot, bbase, row_ptr, nkeys, KBE);
    k_build<<<KBE, 256, 0, stream>>>(staging, bcnt, bbase, row_ptr, csr_src, dinv, perm, N, KBE);
    k_cvt_x<<<((N * D / 4) + 255) / 256, 256, 0, stream>>>(x, dinv, hb0, N * D / 4);
    k_cvt_w<<<((L * D * D) + 255) / 256, 256, 0, stream>>>(convw, Wt, L * D * D);

    const int lblocks = (N + 15) / 16;
    // layer 0: hb0 -> hb1 ; layer 1: hb1 -> hb0 ; layer 2: hb0 -> hrelu
    k_layer<<<lblocks, 256, 0, stream>>>(hb0, row_ptr, csr_src, dinv, perm, Wt,
                                         convb, hb1, hrelu, N, 0);
    k_layer<<<lblocks, 256, 0, stream>>>(hb1, row_ptr, csr_src, dinv, perm, Wt + D * D,
                                         convb + D, hb0, hrelu, N, 0);
    k_layer<<<lblocks, 256, 0, stream>>>(hb0, row_ptr, csr_src, dinv, perm, Wt + 2 * D * D,
                                         convb + 2 * D, hb1, hrelu, N, 1);

    k_pool<<<B * 4, 256, 0, stream>>>(hrelu, gstart, gcnt, pmax, psum, B);
    k_final<<<B, 64, 0, stream>>>(pmax, psum, gcnt, outw, outb, out, B);
}

// Round 12
// 454.732 us; speedup vs baseline: 1.0931x; 1.0931x over previous
//
#include <hip/hip_runtime.h>
#include <hip/hip_bf16.h>

#define D 128
#define NP 8           // src-range sub-buckets per dst (csr slice order)
#define DPB 64         // dst per coarse bucket (b = d>>6)
#define KPB (DPB * NP) // fine keys per bucket = 512
#define SUB 64         // sub-cursors per bucket
#define CAP_SUB 64     // staging capacity per (sub, bucket); mean 16

typedef __attribute__((ext_vector_type(8))) __bf16 bf16x8;
typedef __attribute__((ext_vector_type(4))) float f32x4;
typedef __attribute__((ext_vector_type(4))) short s16x4;
typedef __attribute__((ext_vector_type(8))) short s16x8;

static __device__ __forceinline__ short f2bf(float f) {
    union { float f; unsigned u; } in; in.f = f;
    unsigned u = in.u;
    u += 0x7fffu + ((u >> 16) & 1u);   // round-to-nearest-even
    return (short)(u >> 16);
}

// ---- phase 1: coarse-bucket edges; 100K sub-cursors kill contention ----
// pack: fineKey(9b: (d&63)*8 + (src>>14)) << 17 | src(17b)   [N < 2^17]
__global__ void k_bucket(const int* __restrict__ src, const int* __restrict__ dst,
                         int* __restrict__ bcnt, int* __restrict__ staging,
                         int E, int KBE) {
    int i = blockIdx.x * 256 + threadIdx.x;
    if (i >= E) return;
    int d = dst[i], s = src[i];
    int b = d >> 6;
    int key = ((d & 63) << 3) | (s >> 14);
    int j = blockIdx.x & (SUB - 1);      // j%8 == heuristic XCD
    int slot = atomicAdd(&bcnt[j * KBE + b], 1);
    if (slot < CAP_SUB) staging[((size_t)j * KBE + b) * CAP_SUB + slot] = (key << 17) | s;
}

// ---- per-bucket totals (parallel, coalesced per-j stripes) ----
__global__ void k_btot(const int* __restrict__ bcnt, int* __restrict__ btot, int KBE) {
    int b = blockIdx.x * 256 + threadIdx.x;
    if (b >= KBE) return;
    int v = 0;
    #pragma unroll
    for (int j = 0; j < SUB; j++) {
        int c = bcnt[j * KBE + b];
        v += (c > CAP_SUB) ? CAP_SUB : c;
    }
    btot[b] = v;
}

// ---- exclusive scan of bucket totals (single block, chunked) ----
__global__ void k_bscan(const int* __restrict__ btot, int* __restrict__ bbase,
                        int* __restrict__ row_ptr, int nkeys, int KBE) {
    __shared__ int sm[512];
    __shared__ int carry;
    int t = threadIdx.x;
    if (t == 0) carry = 0;
    __syncthreads();
    for (int c0 = 0; c0 < KBE; c0 += 512) {
        int b = c0 + t;
        int v = (b < KBE) ? btot[b] : 0;
        sm[t] = v;
        __syncthreads();
        for (int off = 1; off < 512; off <<= 1) {
            int x = (t >= off) ? sm[t - off] : 0;
            __syncthreads();
            sm[t] += x;
            __syncthreads();
        }
        if (b < KBE) bbase[b] = sm[t] - v + carry;
        __syncthreads();
        if (t == 0) carry += sm[511];
        __syncthreads();
    }
    if (t == 0) { bbase[KBE] = carry; row_ptr[nkeys] = carry; }
}

// ---- phase 2: per-bucket fine CSR build in LDS; no binary search, no serial prefix ----
// thread t owns lane (t&3) of sub-region j = t>>2  (4 threads per sub, ~16 edges each)
__global__ __launch_bounds__(256) void k_build(
    const int* __restrict__ staging, const int* __restrict__ bcnt,
    const int* __restrict__ bbase, int* __restrict__ row_ptr,
    int* __restrict__ csr_src, float* __restrict__ dinv, int N, int KBE)
{
    const int b = blockIdx.x;
    const int tid = threadIdx.x;
    __shared__ int cnt[KPB];
    __shared__ int subn[SUB];
    __shared__ int chunkbuf[256];
    __shared__ int carry;

    if (tid < SUB) {
        int c = bcnt[tid * KBE + b];
        subn[tid] = (c > CAP_SUB) ? CAP_SUB : c;
    }
    for (int k = tid; k < KPB; k += 256) cnt[k] = 0;
    if (tid == 0) carry = 0;
    __syncthreads();

    const int base = bbase[b];
    const int nb = bbase[b + 1] - base;          // bucket total (from scan)
    const int j = tid >> 2, l4 = tid & 3;
    const int* __restrict__ sreg = staging + ((size_t)j * KBE + b) * CAP_SUB;
    const int sn = subn[j];

    // histogram over fine keys
    for (int e = l4; e < sn; e += 4)
        atomicAdd(&cnt[sreg[e] >> 17], 1);
    __syncthreads();

    // in-place exclusive scan of cnt[0..KPB)  (2 chunks of 256)
    #pragma unroll 1
    for (int c = 0; c < KPB / 256; c++) {
        int idx = c * 256 + tid;
        int v = cnt[idx];
        chunkbuf[tid] = v;
        __syncthreads();
        for (int off = 1; off < 256; off <<= 1) {
            int x = (tid >= off) ? chunkbuf[tid - off] : 0;
            __syncthreads();
            chunkbuf[tid] += x;
            __syncthreads();
        }
        cnt[idx] = chunkbuf[tid] - v + carry;
        __syncthreads();
        if (tid == 255) carry += chunkbuf[255];
        __syncthreads();
    }

    for (int k = tid; k < KPB; k += 256)
        row_ptr[(size_t)b * KPB + k] = base + cnt[k];
    for (int dl = tid; dl < DPB; dl += 256) {
        int d = b * DPB + dl;
        if (d < N) {
            int hi2 = (dl == DPB - 1) ? nb : cnt[(dl + 1) * NP];
            int deg = hi2 - cnt[dl * NP];
            dinv[d] = rsqrtf((float)deg + 1.0f);
        }
    }
    __syncthreads();

    // scatter into this bucket's contiguous csr region (LDS cursors)
    for (int e = l4; e < sn; e += 4) {
        int w = sreg[e];
        int slot = base + atomicAdd(&cnt[w >> 17], 1);
        csr_src[slot] = w & 0x1FFFF;
    }
}

// ---- batch is SORTED: segment starts AND counts via binary search ----
__global__ void k_gseg(const int* __restrict__ batch, int* __restrict__ gstart,
                       int* __restrict__ gcnt, int N, int B) {
    int g = blockIdx.x * blockDim.x + threadIdx.x;
    if (g > B) return;
    int lo = 0, hi = N;
    while (lo < hi) {
        int mid = (lo + hi) >> 1;
        if (batch[mid] < g) lo = mid + 1; else hi = mid;
    }
    gstart[g] = lo;
    if (g < B) {
        int lo2 = lo, hi2 = N;
        while (lo2 < hi2) {
            int mid = (lo2 + hi2) >> 1;
            if (batch[mid] < g + 1) lo2 = mid + 1; else hi2 = mid;
        }
        gcnt[g] = lo2 - lo;
    }
}

// ---- x' = dinv[i] * x  -> bf16 (pre-scaled feature rows) ----
__global__ void k_cvt_x(const float* __restrict__ x, const float* __restrict__ dinv,
                        short* __restrict__ xb, int total4) {
    int i = blockIdx.x * blockDim.x + threadIdx.x;
    if (i < total4) {
        float d = dinv[i >> 5];
        float4 v = ((const float4*)x)[i];
        s16x4 o;
        o.x = f2bf(v.x * d); o.y = f2bf(v.y * d);
        o.z = f2bf(v.z * d); o.w = f2bf(v.w * d);
        ((s16x4*)xb)[i] = o;
    }
}

// ---- conv_w: fp32 [L][k][n] -> bf16 transposed [L][n][k] ----
__global__ void k_cvt_w(const float* __restrict__ W, short* __restrict__ Wt, int total) {
    int i = blockIdx.x * blockDim.x + threadIdx.x;
    if (i < total) {
        int l = i >> 14;
        int rem = i & 16383;
        int n = rem >> 7;
        int k = rem & 127;
        Wt[i] = f2bf(W[(l << 14) + (k << 7) + n]);
    }
}

// ---- FUSED layer v4: round-10 structure + flat 4-deep gather chains ----
// 16 concurrent nodes/block (1 per 16-lane group, sequential ids) -> 4KB LDS
// tile -> 1 barrier -> cooperative 16x128 MFMA GEMM (wave w = 32 cols).
// Flat loop over the node's full contiguous csr range (slice-ordered): full
// 4-deep chains (no pass-boundary breaks), only 4 live bf16x8 (VGPR ~32).
// mode 0: hout[r] = bf16( relu(C + b) * dinv[r] );  mode 1: hrelu[r] = fp32 relu(C+b)
__global__ __launch_bounds__(256) void k_layer(
    const short* __restrict__ hin, const int* __restrict__ row_ptr,
    const int* __restrict__ csr_src, const float* __restrict__ dinv,
    const short* __restrict__ Wt, const float* __restrict__ bias,
    short* __restrict__ hout, float* __restrict__ hrelu, int N, int mode)
{
    __shared__ __align__(16) short tile[16 * 128];   // 4 KB, swizzled 16B chunks
    const int tid = threadIdx.x;
    const int wave = tid >> 6;
    const int lane = tid & 63;
    const int group = lane >> 4;
    const int lg = lane & 15;
    const int off = lg * 8;
    const int node_base = blockIdx.x * 16;
    const int r = wave * 4 + group;          // tile row this group owns (0..15)
    const int i = node_base + r;

    // ---- phase 1: aggregate one node per group (16 concurrent per block) ----
    short* dstp = &tile[r * 128 + ((lg ^ (r & 7)) << 3)];
    if (i < N) {
        float acc[8];
        bf16x8 v = *(const bf16x8*)(hin + (size_t)i * D + off);
        #pragma unroll
        for (int k = 0; k < 8; k++) acc[k] = (float)v[k];

        int t = row_ptr[i * NP];
        const int end = row_ptr[i * NP + NP];
        for (; t + 4 <= end; t += 4) {       // full 4-deep chains, no pass breaks
            int i0 = csr_src[t + 0], i1 = csr_src[t + 1];
            int i2 = csr_src[t + 2], i3 = csr_src[t + 3];
            bf16x8 v0 = *(const bf16x8*)(hin + (size_t)i0 * D + off);
            bf16x8 v1 = *(const bf16x8*)(hin + (size_t)i1 * D + off);
            bf16x8 v2 = *(const bf16x8*)(hin + (size_t)i2 * D + off);
            bf16x8 v3 = *(const bf16x8*)(hin + (size_t)i3 * D + off);
            #pragma unroll
            for (int k = 0; k < 8; k++)
                acc[k] += (((float)v0[k] + (float)v1[k]) + ((float)v2[k] + (float)v3[k]));
        }
        for (; t < end; t++) {               // scalar tail (<=3)
            int i0 = csr_src[t];
            bf16x8 v0 = *(const bf16x8*)(hin + (size_t)i0 * D + off);
            #pragma unroll
            for (int k = 0; k < 8; k++) acc[k] += (float)v0[k];
        }

        const float di = dinv[i];
        s16x8 o;
        #pragma unroll
        for (int k = 0; k < 8; k++) o[k] = f2bf(acc[k] * di);
        *(s16x8*)dstp = o;
    } else {
        s16x8 z = {0, 0, 0, 0, 0, 0, 0, 0};
        *(s16x8*)dstp = z;
    }
    __syncthreads();

    // ---- phase 2: cooperative GEMM; wave w computes cols [w*32, w*32+32) ----
    bf16x8 afrag[4];
    #pragma unroll
    for (int kt = 0; kt < 4; kt++)
        afrag[kt] = *(const bf16x8*)(&tile[lg * 128 + (((group + 4 * kt) ^ (lg & 7)) << 3)]);

    f32x4 acc2[2];
    #pragma unroll
    for (int nt = 0; nt < 2; nt++) { f32x4 z = {0.f, 0.f, 0.f, 0.f}; acc2[nt] = z; }
    #pragma unroll
    for (int nt = 0; nt < 2; nt++) {
        const short* bp = Wt + (size_t)(wave * 32 + nt * 16 + lg) * D + group * 8;
        #pragma unroll
        for (int kt = 0; kt < 4; kt++) {
            bf16x8 b = *(const bf16x8*)(bp + kt * 32);
            acc2[nt] = __builtin_amdgcn_mfma_f32_16x16x32_bf16(afrag[kt], b, acc2[nt], 0, 0, 0);
        }
    }

    // C/D layout: col = lane&15, row = (lane>>4)*4 + reg
    float bcol[2];
    #pragma unroll
    for (int nt = 0; nt < 2; nt++) bcol[nt] = bias[wave * 32 + nt * 16 + lg];
    const int row0 = node_base + group * 4;
    #pragma unroll
    for (int i2 = 0; i2 < 4; i2++) {
        int r2 = row0 + i2;
        if (r2 < N) {
            if (mode == 0) {
                float dr = dinv[r2];
                #pragma unroll
                for (int nt = 0; nt < 2; nt++) {
                    int col = wave * 32 + nt * 16 + lg;
                    float val = fmaxf(acc2[nt][i2] + bcol[nt], 0.0f);
                    hout[(size_t)r2 * D + col] = f2bf(val * dr);
                }
            } else {
                #pragma unroll
                for (int nt = 0; nt < 2; nt++) {
                    int col = wave * 32 + nt * 16 + lg;
                    hrelu[(size_t)r2 * D + col] = fmaxf(acc2[nt][i2] + bcol[nt], 0.0f);
                }
            }
        }
    }
}

// ---- segmented pooling, 4-way row-split per graph for latency hiding ----
__global__ __launch_bounds__(256) void k_pool(const float* __restrict__ hrelu,
                                              const int* __restrict__ gstart,
                                              const int* __restrict__ gcnt,
                                              float* __restrict__ pmax,
                                              float* __restrict__ psum, int B) {
    int g = blockIdx.x >> 2;
    int q = blockIdx.x & 3;
    int c = threadIdx.x & 127;
    int p = threadIdx.x >> 7;
    int start = gstart[g];
    int endr = start + gcnt[g];

    float mx0 = 0.f, mx1 = 0.f, sm0 = 0.f, sm1 = 0.f;
    int r = start + q * 2 + p;
    for (; r + 8 < endr; r += 16) {
        float v0 = hrelu[(size_t)r * D + c];
        float v1 = hrelu[(size_t)(r + 8) * D + c];
        mx0 = fmaxf(mx0, v0); sm0 += v0;
        mx1 = fmaxf(mx1, v1); sm1 += v1;
    }
    if (r < endr) {
        float v0 = hrelu[(size_t)r * D + c];
        mx0 = fmaxf(mx0, v0); sm0 += v0;
    }
    float mx = fmaxf(mx0, mx1), sm = sm0 + sm1;

    __shared__ float smx[128], ssm[128];
    if (p == 1) { smx[c] = mx; ssm[c] = sm; }
    __syncthreads();
    if (p == 0) {
        pmax[((size_t)q * B + g) * D + c] = fmaxf(mx, smx[c]);
        psum[((size_t)q * B + g) * D + c] = sm + ssm[c];
    }
}

// ---- final: combine 4 partials; out[g] = [gmax, gsum/cnt, gsum] @ out_w + out_b ----
__global__ void k_final(const float* __restrict__ pmax, const float* __restrict__ psum,
                        const int* __restrict__ gcnt, const float* __restrict__ ow,
                        const float* __restrict__ ob, float* __restrict__ out, int B) {
    int g = blockIdx.x;
    int t = threadIdx.x;  // 64
    float part[10];
    #pragma unroll
    for (int o = 0; o < 10; o++) part[o] = 0.f;
    float invc = 1.0f / fmaxf((float)gcnt[g], 1.0f);
    for (int k = t; k < 3 * D; k += 64) {
        int c = (k < D) ? k : ((k < 2 * D) ? k - D : k - 2 * D);
        float pk;
        if (k < D) {
            float m = pmax[(size_t)g * D + c];
            #pragma unroll
            for (int q = 1; q < 4; q++) m = fmaxf(m, pmax[((size_t)q * B + g) * D + c]);
            pk = m;
        } else {
            float s = psum[(size_t)g * D + c];
            #pragma unroll
            for (int q = 1; q < 4; q++) s += psum[((size_t)q * B + g) * D + c];
            pk = (k < 2 * D) ? s * invc : s;
        }
        const float* w = ow + k * 10;
        #pragma unroll
        for (int o = 0; o < 10; o++) part[o] += pk * w[o];
    }
    #pragma unroll
    for (int off = 32; off > 0; off >>= 1)
        #pragma unroll
        for (int o = 0; o < 10; o++) part[o] += __shfl_down(part[o], off, 64);
    if (t == 0)
        #pragma unroll
        for (int o = 0; o < 10; o++) out[g * 10 + o] = part[o] + ob[o];
}

extern "C" void kernel_launch(void* const* d_in, const int* in_sizes, int n_in,
                              void* d_out, int out_size, void* d_ws, size_t ws_size,
                              hipStream_t stream) {
    const float* x     = (const float*)d_in[0];
    const int*   ei    = (const int*)d_in[1];
    const int*   batch = (const int*)d_in[2];
    const float* convw = (const float*)d_in[3];
    const float* convb = (const float*)d_in[4];
    const float* outw  = (const float*)d_in[5];
    const float* outb  = (const float*)d_in[6];
    float* out = (float*)d_out;

    const int N = in_sizes[0] / D;        // 100000
    const int E = in_sizes[1] / 2;        // 1600000
    const int L = in_sizes[3] / (D * D);  // 3
    const int B = out_size / 10;          // 256

    const int* src = ei;
    const int* dst = ei + E;

    const int KBE   = (N + DPB - 1) / DPB;     // coarse buckets (1563)
    const int nkeys = KBE * KPB;               // global fine-key space

    char* p = (char*)d_ws;
    auto alloc = [&](size_t bytes) { char* r = p; p += (bytes + 255) & ~255ull; return r; };
    short* hb0     = (short*)alloc((size_t)N * D * 2);      // ping-pong bf16 rows
    short* hb1     = (short*)alloc((size_t)N * D * 2);
    float* hrelu   = (float*)alloc((size_t)N * D * 4);      // fp32 last-layer relu; ALIASED as staging
    short* Wt      = (short*)alloc((size_t)L * D * D * 2);  // bf16 W^T
    int*   row_ptr = (int*)alloc(((size_t)nkeys + 1) * 4);
    int*   csr_src = (int*)alloc((size_t)E * 4);
    int*   bcnt    = (int*)alloc((size_t)SUB * KBE * 4);
    int*   btot    = (int*)alloc((size_t)KBE * 4);
    int*   bbase   = (int*)alloc(((size_t)KBE + 1) * 4);
    float* dinv    = (float*)alloc((size_t)N * 4);
    float* pmax    = (float*)alloc((size_t)4 * B * D * 4);
    float* psum    = (float*)alloc((size_t)4 * B * D * 4);
    int*   gcnt    = (int*)alloc((size_t)B * 4);
    int*   gstart  = (int*)alloc(((size_t)B + 1) * 4);

    // staging: SUB*KBE*CAP_SUB*4 = 64*1563*64*4 = 25.6 MB <= hrelu's 51.2 MB
    int* staging = (int*)hrelu;   // hrelu written only after k_build completes

    hipMemsetAsync(bcnt, 0, (size_t)SUB * KBE * 4, stream);

    k_bucket<<<(E + 255) / 256, 256, 0, stream>>>(src, dst, bcnt, staging, E, KBE);
    k_gseg<<<1, 512, 0, stream>>>(batch, gstart, gcnt, N, B);
    k_btot<<<(KBE + 255) / 256, 256, 0, stream>>>(bcnt, btot, KBE);
    k_bscan<<<1, 512, 0, stream>>>(btot, bbase, row_ptr, nkeys, KBE);
    k_build<<<KBE, 256, 0, stream>>>(staging, bcnt, bbase, row_ptr, csr_src, dinv, N, KBE);
    k_cvt_x<<<((N * D / 4) + 255) / 256, 256, 0, stream>>>(x, dinv, hb0, N * D / 4);
    k_cvt_w<<<((L * D * D) + 255) / 256, 256, 0, stream>>>(convw, Wt, L * D * D);

    const int lblocks = (N + 15) / 16;
    // layer 0: hb0 -> hb1 ; layer 1: hb1 -> hb0 ; layer 2: hb0 -> hrelu
    k_layer<<<lblocks, 256, 0, stream>>>(hb0, row_ptr, csr_src, dinv, Wt,
                                         convb, hb1, hrelu, N, 0);
    k_layer<<<lblocks, 256, 0, stream>>>(hb1, row_ptr, csr_src, dinv, Wt + D * D,
                                         convb + D, hb0, hrelu, N, 0);
    k_layer<<<lblocks, 256, 0, stream>>>(hb0, row_ptr, csr_src, dinv, Wt + 2 * D * D,
                                         convb + 2 * D, hb1, hrelu, N, 1);

    k_pool<<<B * 4, 256, 0, stream>>>(hrelu, gstart, gcnt, pmax, psum, B);
    k_final<<<B, 64, 0, stream>>>(pmax, psum, gcnt, outw, outb, out, B);
}